// Round 1
// baseline (735.324 us; speedup 1.0000x reference)
//
#include <hip/hip_runtime.h>

// NeuromodulatedAttention — MI355X (gfx950)
//
// KEY INSIGHT: the dopamine/serotonin "mod" term is a per-row constant added to
// scores BEFORE a per-row mean/std normalization -> it cancels EXACTLY.
// The entropy + both MLPs are dead code. Effective computation:
//   out = softmax( (S - mean(S)) / (std(S,ddof=1) + 1e-6) ) @ V,  S = Q K^T / sqrt(512)
//
// Design: zero-workspace fused kernel. Grid = 4 (batch) x 64 (q-tiles of 32 rows),
// 256 threads = 4 waves, waves split the k dimension (32 k-rows each per 128-k iter).
// Pass 1: QK^T via mfma_f32_32x32x16_bf16, accumulate per-row sum/sumsq (registers),
//         block-reduce -> mean, 1/(std+1e-6).
// Pass 2: recompute QK^T, p = exp(norm(s)), P round-trips through LDS (C-layout ->
//         A-layout), PV via MFMA with V staged transposed in LDS; divide by row sum.
//
// MFMA 32x32x16_bf16 layouts (m74/m101-verified C/D; A/B by the measured pattern):
//   A[m][k]: m = lane&31, k = (lane>>5)*8 + j   (8 contiguous bf16 per lane)
//   B[k][n]: n = lane&31, k = (lane>>5)*8 + j
//   D[row][col]: col = lane&31, row = (reg&3) + 8*(reg>>2) + 4*(lane>>5)

#define BB 4
#define SS 2048
#define DD 512

typedef __bf16 bf16;
typedef bf16 bf16x2 __attribute__((ext_vector_type(2)));
typedef bf16 bf16x4 __attribute__((ext_vector_type(4)));
typedef bf16 bf16x8 __attribute__((ext_vector_type(8)));
typedef float f32x16 __attribute__((ext_vector_type(16)));

#define QS_STRIDE 520   // 1040B: 16B-aligned rows, bank start 4*row -> phase-tiled
#define KS_STRIDE 72    // 144B:  16B-aligned, bank start 4*row
#define VT_STRIDE 18    // 36B:   b32 reads (9dw odd stride -> 2-way max, free)
#define PS_STRIDE 136   // 272B:  16B-aligned, bank start 4*row
#define SCALE 0.044194173824159216f  // 1/sqrt(512)
#define LOG2E 1.4426950408889634f

// Compute one 32x32 score tile (q = block rows, k = this wave's 32 rows),
// accumulating over all 512 d in chunks of 64 staged into wave-private LDS.
__device__ __forceinline__ f32x16 qk_tile(const float* __restrict__ Kb,
                                          const bf16* __restrict__ Qs,
                                          bf16* __restrict__ KVw,
                                          int l31, int lh8, int lane) {
  f32x16 acc = {};
  for (int dc = 0; dc < DD; dc += 64) {
    // stage K chunk: 32 rows x 64 cols fp32 -> bf16 (wave-private, no barrier)
#pragma unroll
    for (int i = 0; i < 8; ++i) {
      int f = i * 64 + lane;          // 512 float4 over 32 rows x 16 f4
      int row = f >> 4;
      int c4 = (f & 15) * 4;
      float4 v = *(const float4*)(Kb + row * DD + dc + c4);
      bf16x4 h = { (bf16)v.x, (bf16)v.y, (bf16)v.z, (bf16)v.w };
      *(bf16x4*)&KVw[row * KS_STRIDE + c4] = h;
    }
#pragma unroll
    for (int ks = 0; ks < 4; ++ks) {
      bf16x8 a  = *(const bf16x8*)&Qs[l31 * QS_STRIDE + dc + ks * 16 + lh8];
      bf16x8 bb = *(const bf16x8*)&KVw[l31 * KS_STRIDE + ks * 16 + lh8];
      acc = __builtin_amdgcn_mfma_f32_32x32x16_bf16(a, bb, acc, 0, 0, 0);
    }
  }
  return acc;
}

__launch_bounds__(256, 1)
__global__ void nm_attn_kernel(const float* __restrict__ Qp,
                               const float* __restrict__ Kp,
                               const float* __restrict__ Vp,
                               float* __restrict__ Op) {
  __shared__ bf16 Qs[32 * QS_STRIDE];        // 33,280 B  (full-d Q tile, bf16)
  __shared__ bf16 KVu[4][32 * KS_STRIDE];    // 18,432 B  per-wave K chunk / Vt union
  __shared__ bf16 Ps[32 * PS_STRIDE];        //  8,704 B  P tile (32q x 128k)
  __shared__ float redA[4][32];              // reductions
  __shared__ float redB[4][32];
  __shared__ float a0v[32], a1v[32], idv[32];
  // total ~61.8 KB static LDS

  const int tid  = threadIdx.x;
  const int w    = tid >> 6;
  const int lane = tid & 63;
  const int l31  = lane & 31;
  const int lh   = lane >> 5;
  const int lh8  = lh * 8;
  const int b    = blockIdx.y;
  const int q0   = blockIdx.x * 32;

  // ---- load Q tile (32 x 512) fp32 -> bf16 LDS ----
  {
    const float* Qbase = Qp + (size_t)(b * SS + q0) * DD;
#pragma unroll
    for (int i = 0; i < 16; ++i) {
      int f = i * 256 + tid;          // 4096 float4
      int row = f >> 7;
      int c4 = (f & 127) * 4;
      float4 v = *(const float4*)(Qbase + row * DD + c4);
      bf16x4 h = { (bf16)v.x, (bf16)v.y, (bf16)v.z, (bf16)v.w };
      *(bf16x4*)&Qs[row * QS_STRIDE + c4] = h;
    }
  }
  __syncthreads();

  int qrow[16];
#pragma unroll
  for (int r = 0; r < 16; ++r) qrow[r] = (r & 3) + 8 * (r >> 2) + 4 * lh;

  // ================= PASS 1: row stats =================
  float sumv[16], sqv[16];
#pragma unroll
  for (int r = 0; r < 16; ++r) { sumv[r] = 0.f; sqv[r] = 0.f; }

  for (int kt = 0; kt < 16; ++kt) {
    const float* Kb = Kp + (size_t)(b * SS + kt * 128 + w * 32) * DD;
    f32x16 acc = qk_tile(Kb, Qs, KVu[w], l31, lh8, lane);
#pragma unroll
    for (int r = 0; r < 16; ++r) {
      float s = acc[r] * SCALE;
      sumv[r] += s;
      sqv[r]  += s * s;
    }
  }

  // reduce stats over the 32 k-lanes (each half-wave independently)
#pragma unroll
  for (int r = 0; r < 16; ++r) {
    float v1 = sumv[r], v2 = sqv[r];
#pragma unroll
    for (int m = 16; m >= 1; m >>= 1) {
      v1 += __shfl_xor(v1, m);
      v2 += __shfl_xor(v2, m);
    }
    if (l31 == 0) { redA[w][qrow[r]] = v1; redB[w][qrow[r]] = v2; }
  }
  __syncthreads();
  if (tid < 32) {
    float s  = redA[0][tid] + redA[1][tid] + redA[2][tid] + redA[3][tid];
    float sq = redB[0][tid] + redB[1][tid] + redB[2][tid] + redB[3][tid];
    float mean = s * (1.0f / 2048.0f);
    float var = (sq - 2048.0f * mean * mean) * (1.0f / 2047.0f);
    var = fmaxf(var, 0.0f);
    float istd = 1.0f / (sqrtf(var) + 1e-6f);
    a1v[tid] = istd * LOG2E;           // p = exp2(s*a1 + a0) = exp((s-mean)*istd)
    a0v[tid] = -mean * istd * LOG2E;
  }
  __syncthreads();

  float a0r[16], a1r[16], den[16];
#pragma unroll
  for (int r = 0; r < 16; ++r) {
    a0r[r] = a0v[qrow[r]];
    a1r[r] = a1v[qrow[r]];
    den[r] = 0.f;
  }

  // ================= PASS 2: softmax + PV =================
  f32x16 Oa[4] = {};   // 32q x 128d per wave (wave w owns d in [w*128, w*128+128))

  for (int kt = 0; kt < 16; ++kt) {
    const float* Kb = Kp + (size_t)(b * SS + kt * 128 + w * 32) * DD;
    f32x16 acc = qk_tile(Kb, Qs, KVu[w], l31, lh8, lane);

    __syncthreads();   // previous iteration's PV reads of Ps are done
#pragma unroll
    for (int r = 0; r < 16; ++r) {
      float s = acc[r] * SCALE;
      float p = exp2f(fmaf(s, a1r[r], a0r[r]));
      den[r] += p;
      Ps[qrow[r] * PS_STRIDE + w * 32 + l31] = (bf16)p;
    }
    __syncthreads();   // Ps tile (32q x 128k) complete for all waves

    // PV over this 128-k chunk; V staged transposed per 16-k sub-chunk
    const float* Vb = Vp + (size_t)(b * SS + kt * 128) * DD + w * 128 + 2 * lane;
    bf16* Vt = KVu[w];
    const int d0 = 2 * lane;
    for (int ks2 = 0; ks2 < 8; ++ks2) {
      const float* Vk = Vb + ks2 * 16 * DD;
#pragma unroll
      for (int i = 0; i < 8; ++i) {
        float2 va = *(const float2*)(Vk + (2 * i) * DD);
        float2 vc = *(const float2*)(Vk + (2 * i + 1) * DD);
        bf16x2 h0 = { (bf16)va.x, (bf16)vc.x };
        bf16x2 h1 = { (bf16)va.y, (bf16)vc.y };
        *(bf16x2*)&Vt[d0 * VT_STRIDE + 2 * i] = h0;
        *(bf16x2*)&Vt[(d0 + 1) * VT_STRIDE + 2 * i] = h1;
      }
      bf16x8 aP = *(const bf16x8*)&Ps[l31 * PS_STRIDE + ks2 * 16 + lh8];
#pragma unroll
      for (int dt = 0; dt < 4; ++dt) {
        const bf16* vr = &Vt[(dt * 32 + l31) * VT_STRIDE + lh8];
        bf16x2 e0 = *(const bf16x2*)(vr + 0);
        bf16x2 e1 = *(const bf16x2*)(vr + 2);
        bf16x2 e2 = *(const bf16x2*)(vr + 4);
        bf16x2 e3 = *(const bf16x2*)(vr + 6);
        bf16x8 bV = { e0.x, e0.y, e1.x, e1.y, e2.x, e2.y, e3.x, e3.y };
        Oa[dt] = __builtin_amdgcn_mfma_f32_32x32x16_bf16(aP, bV, Oa[dt], 0, 0, 0);
      }
    }
  }

  // ---- denominator reduction ----
#pragma unroll
  for (int r = 0; r < 16; ++r) {
    float v1 = den[r];
#pragma unroll
    for (int m = 16; m >= 1; m >>= 1) v1 += __shfl_xor(v1, m);
    if (l31 == 0) redA[w][qrow[r]] = v1;
  }
  __syncthreads();
  if (tid < 32) {
    float t = redA[0][tid] + redA[1][tid] + redA[2][tid] + redA[3][tid];
    idv[tid] = 1.0f / t;
  }
  __syncthreads();

  float idr[16];
#pragma unroll
  for (int r = 0; r < 16; ++r) idr[r] = idv[qrow[r]];

  // ---- write output: rows q0+qrow[r], cols w*128 + dt*32 + l31 ----
  float* Ob = Op + (size_t)(b * SS + q0) * DD + w * 128;
#pragma unroll
  for (int dt = 0; dt < 4; ++dt) {
#pragma unroll
    for (int r = 0; r < 16; ++r) {
      Ob[qrow[r] * DD + dt * 32 + l31] = Oa[dt][r] * idr[r];
    }
  }
}

extern "C" void kernel_launch(void* const* d_in, const int* in_sizes, int n_in,
                              void* d_out, int out_size, void* d_ws, size_t ws_size,
                              hipStream_t stream) {
  // inputs: 0=Q 1=K 2=V (fp32); indices 3..12 (MLP weights, scales) are dead code
  // because the per-row "mod" cancels under the per-row mean/std normalization.
  const float* Q = (const float*)d_in[0];
  const float* K = (const float*)d_in[1];
  const float* V = (const float*)d_in[2];
  float* out = (float*)d_out;
  (void)d_ws; (void)ws_size; (void)in_sizes; (void)n_in; (void)out_size;

  dim3 grid(SS / 32, BB, 1);   // 64 q-tiles x 4 batches = 256 blocks (1 per CU)
  nm_attn_kernel<<<grid, dim3(256, 1, 1), 0, stream>>>(Q, K, V, out);
}

// Round 2
// 302.000 us; speedup vs baseline: 2.4348x; 2.4348x over previous
//
#include <hip/hip_runtime.h>

// NeuromodulatedAttention — MI355X (gfx950), round 2
//
// ALGEBRA: (1) the dopamine/serotonin "mod" is a per-row constant added before
// per-row mean/std normalization -> cancels exactly (MLPs are dead code).
// (2) the mean subtraction is a per-row constant inside softmax -> also cancels.
// Effective computation:  out = softmax( S * istd_row ) @ V,
//   S = Q K^T / sqrt(512),  istd_row = 1/(std(S_row, ddof=1) + 1e-6).
//
// Round-2 structure (ws-gated fast path):
//   precast: Q,K -> bf16 [b][s][d]; V -> bf16 transposed [b][d][s]  (25.2 MB ws)
//   attn: 256 blocks x 512 thr (8 waves). Q-tile 32 rows. Per-wave MFMA B-frags
//   are DIRECT global 16B loads (line-coalesced) from bf16 K / transposed V —
//   no K/V LDS staging, no staging barriers, loads stream from per-XCD L2
//   (batch pinned to an XCD pair by block swizzle). Q and P tiles live in two
//   32KB XOR-swizzled LDS tiles (64KB total, 2 blocks/CU LDS-wise).
//   Pass 1: row sum/sumsq of S (4 accs/wave, 4 MFMA per A-read).
//   Pass 2: recompute S, p = exp2(s*a1), P -> LDS, PV from transposed V;
//   denominator summed from the bf16 P fragments (numerator-consistent).

#define BB 4
#define SS 2048
#define DD 512
#define SCALE 0.044194173824159216f  // 1/sqrt(512)
#define LOG2E 1.4426950408889634f

typedef __bf16 bf16;
typedef bf16 bf16x4 __attribute__((ext_vector_type(4)));
typedef bf16 bf16x8 __attribute__((ext_vector_type(8)));
typedef float f32x16 __attribute__((ext_vector_type(16)));

// ---------------- precast kernels ----------------

__global__ void cast_qk_kernel(const float* __restrict__ Q, const float* __restrict__ K,
                               bf16* __restrict__ Qb, bf16* __restrict__ Kb) {
  size_t i = ((size_t)blockIdx.x * 256 + threadIdx.x) * 8;
  float4 a0 = *(const float4*)(Q + i);
  float4 a1 = *(const float4*)(Q + i + 4);
  bf16x8 qa = { (bf16)a0.x, (bf16)a0.y, (bf16)a0.z, (bf16)a0.w,
                (bf16)a1.x, (bf16)a1.y, (bf16)a1.z, (bf16)a1.w };
  *(bf16x8*)(Qb + i) = qa;
  float4 b0 = *(const float4*)(K + i);
  float4 b1 = *(const float4*)(K + i + 4);
  bf16x8 ka = { (bf16)b0.x, (bf16)b0.y, (bf16)b0.z, (bf16)b0.w,
                (bf16)b1.x, (bf16)b1.y, (bf16)b1.z, (bf16)b1.w };
  *(bf16x8*)(Kb + i) = ka;
}

__global__ void transpose_v_kernel(const float* __restrict__ V, bf16* __restrict__ Vt) {
  __shared__ bf16 tile[32][33];
  int b = blockIdx.z;
  int s0 = blockIdx.x * 32, d0 = blockIdx.y * 32;
  int tx = threadIdx.x & 31, ty = threadIdx.x >> 5;  // ty 0..7
#pragma unroll
  for (int i = 0; i < 4; ++i) {
    int r = ty + i * 8;
    tile[r][tx] = (bf16)V[((size_t)b * SS + s0 + r) * DD + d0 + tx];
  }
  __syncthreads();
#pragma unroll
  for (int i = 0; i < 4; ++i) {
    int r = ty + i * 8;
    Vt[((size_t)b * DD + d0 + r) * SS + s0 + tx] = tile[tx][r];
  }
}

// ---------------- main attention kernel (fast path) ----------------

// XOR-swizzled element index inside a 32x512 bf16 LDS tile: balanced banks for
// both the row-major b128 staging writes and the A-fragment b128 reads.
__device__ __forceinline__ int sw(int row, int col) {
  return row * 512 + ((((col >> 3) ^ (row & 7))) << 3) + (col & 7);
}

__launch_bounds__(512, 2)
__global__ void nm_attn2_kernel(const bf16* __restrict__ Qw,
                                const bf16* __restrict__ Kw,
                                const bf16* __restrict__ Vw,
                                float* __restrict__ Op) {
  __shared__ bf16 Qs[32 * 512];   // 32 KB, swizzled
  __shared__ bf16 Ps[32 * 512];   // 32 KB, swizzled; stats scratch overlaid
  float* scratch = (float*)Ps;

  const int tid  = threadIdx.x;
  const int w    = tid >> 6;          // wave 0..7
  const int lane = tid & 63;
  const int l31  = lane & 31;
  const int lh   = lane >> 5;
  const int lh8  = lh * 8;
  const int bid  = blockIdx.x;
  // XCD swizzle: consecutive blocks round-robin XCDs; pin batch b to XCDs {2b,2b+1}
  const int b  = (bid & 7) >> 1;
  const int qt = ((bid >> 3) << 1) | (bid & 1);
  const int q0 = qt * 32;

  // ---- stage Q tile (32 x 512 bf16) into swizzled LDS ----
  {
    const bf16* Qb = Qw + ((size_t)b * SS + q0) * DD;
#pragma unroll
    for (int i = 0; i < 4; ++i) {
      int f = i * 512 + tid;
      int row = f >> 6, g = f & 63;
      bf16x8 v = *(const bf16x8*)&Qb[(size_t)row * DD + g * 8];
      *(bf16x8*)&Qs[row * 512 + ((g ^ (row & 7)) << 3)] = v;
    }
  }
  __syncthreads();

  int qrow[16];
#pragma unroll
  for (int r = 0; r < 16; ++r) qrow[r] = (r & 3) + 8 * (r >> 2) + 4 * lh;

  // ================= PASS 1: row sum / sumsq of scaled scores =================
  float sumv[16], sqv[16];
#pragma unroll
  for (int r = 0; r < 16; ++r) { sumv[r] = 0.f; sqv[r] = 0.f; }

  for (int kt = 0; kt < 2; ++kt) {
    const bf16* Kb = Kw + ((size_t)b * SS + kt * 1024 + w * 128) * DD;
    f32x16 c0 = {}, c1 = {}, c2 = {}, c3 = {};
#pragma unroll 2
    for (int kk = 0; kk < 32; ++kk) {
      bf16x8 af = *(const bf16x8*)&Qs[sw(l31, kk * 16 + lh8)];
      bf16x8 b0 = *(const bf16x8*)&Kb[(size_t)(l31)      * DD + kk * 16 + lh8];
      bf16x8 b1 = *(const bf16x8*)&Kb[(size_t)(32 + l31) * DD + kk * 16 + lh8];
      bf16x8 b2 = *(const bf16x8*)&Kb[(size_t)(64 + l31) * DD + kk * 16 + lh8];
      bf16x8 b3 = *(const bf16x8*)&Kb[(size_t)(96 + l31) * DD + kk * 16 + lh8];
      c0 = __builtin_amdgcn_mfma_f32_32x32x16_bf16(af, b0, c0, 0, 0, 0);
      c1 = __builtin_amdgcn_mfma_f32_32x32x16_bf16(af, b1, c1, 0, 0, 0);
      c2 = __builtin_amdgcn_mfma_f32_32x32x16_bf16(af, b2, c2, 0, 0, 0);
      c3 = __builtin_amdgcn_mfma_f32_32x32x16_bf16(af, b3, c3, 0, 0, 0);
    }
#pragma unroll
    for (int r = 0; r < 16; ++r) {
      float s;
      s = c0[r] * SCALE; sumv[r] += s; sqv[r] += s * s;
      s = c1[r] * SCALE; sumv[r] += s; sqv[r] += s * s;
      s = c2[r] * SCALE; sumv[r] += s; sqv[r] += s * s;
      s = c3[r] * SCALE; sumv[r] += s; sqv[r] += s * s;
    }
  }

  // reduce over the 32 k-columns (lanes l31 within each half-wave)
#pragma unroll
  for (int r = 0; r < 16; ++r) {
    float v1 = sumv[r], v2 = sqv[r];
#pragma unroll
    for (int m = 16; m >= 1; m >>= 1) { v1 += __shfl_xor(v1, m); v2 += __shfl_xor(v2, m); }
    sumv[r] = v1; sqv[r] = v2;
  }
  if (l31 == 0) {
#pragma unroll
    for (int r = 0; r < 16; ++r) {
      scratch[w * 32 + qrow[r]]       = sumv[r];
      scratch[256 + w * 32 + qrow[r]] = sqv[r];
    }
  }
  __syncthreads();
  if (tid < 32) {
    float s = 0.f, q = 0.f;
#pragma unroll
    for (int w2 = 0; w2 < 8; ++w2) { s += scratch[w2 * 32 + tid]; q += scratch[256 + w2 * 32 + tid]; }
    float mean = s * (1.0f / 2048.0f);
    float var  = (q - 2048.0f * mean * mean) * (1.0f / 2047.0f);
    var = fmaxf(var, 0.0f);
    // p = exp((s*SCALE)*istd) up to the per-row constant exp(-mean*istd), which
    // cancels in softmax; a1 folds SCALE*istd*log2(e) for exp2.
    scratch[512 + tid] = SCALE * LOG2E / (sqrtf(var) + 1e-6f);
  }
  __syncthreads();
  float a1r[16];
#pragma unroll
  for (int r = 0; r < 16; ++r) a1r[r] = scratch[512 + qrow[r]];
  __syncthreads();  // scratch reads done before Ps is reused as the P tile

  // ================= PASS 2: softmax + PV =================
  f32x16 O0 = {}, O1 = {};   // wave w owns d in [w*64, w*64+64): two 32-col tiles
  float den = 0.f;           // per-lane: row l31, this lh-half's columns

  for (int kt = 0; kt < 4; ++kt) {
    const bf16* Kb = Kw + ((size_t)b * SS + kt * 512 + w * 64) * DD;
    f32x16 s0 = {}, s1 = {};
#pragma unroll 4
    for (int kk = 0; kk < 32; ++kk) {
      bf16x8 af = *(const bf16x8*)&Qs[sw(l31, kk * 16 + lh8)];
      bf16x8 b0 = *(const bf16x8*)&Kb[(size_t)(l31)      * DD + kk * 16 + lh8];
      bf16x8 b1 = *(const bf16x8*)&Kb[(size_t)(32 + l31) * DD + kk * 16 + lh8];
      s0 = __builtin_amdgcn_mfma_f32_32x32x16_bf16(af, b0, s0, 0, 0, 0);
      s1 = __builtin_amdgcn_mfma_f32_32x32x16_bf16(af, b1, s1, 0, 0, 0);
    }
#pragma unroll
    for (int r = 0; r < 16; ++r) {
      float p0 = exp2f(s0[r] * a1r[r]);
      float p1 = exp2f(s1[r] * a1r[r]);
      Ps[sw(qrow[r], w * 64 + l31)]      = (bf16)p0;
      Ps[sw(qrow[r], w * 64 + 32 + l31)] = (bf16)p1;
    }
    __syncthreads();  // P tile complete (also: prior PV reads done before write)

    const bf16* Vb = Vw + ((size_t)b * DD + w * 64) * SS + kt * 512;
#pragma unroll 4
    for (int kk = 0; kk < 32; ++kk) {
      bf16x8 pf = *(const bf16x8*)&Ps[sw(l31, kk * 16 + lh8)];
      bf16x8 v0 = *(const bf16x8*)&Vb[(size_t)(l31)      * SS + kk * 16 + lh8];
      bf16x8 v1 = *(const bf16x8*)&Vb[(size_t)(32 + l31) * SS + kk * 16 + lh8];
      O0 = __builtin_amdgcn_mfma_f32_32x32x16_bf16(pf, v0, O0, 0, 0, 0);
      O1 = __builtin_amdgcn_mfma_f32_32x32x16_bf16(pf, v1, O1, 0, 0, 0);
      // denominator from the same bf16 P values the numerator uses
      union { bf16x8 h; unsigned u[4]; } cv; cv.h = pf;
#pragma unroll
      for (int j = 0; j < 4; ++j) {
        den += __uint_as_float(cv.u[j] << 16) + __uint_as_float(cv.u[j] & 0xffff0000u);
      }
    }
    __syncthreads();  // PV reads done before next kt overwrites Ps
  }

  // den: combine the two lh halves -> every lane has full row-l31 denominator
  den += __shfl_xor(den, 32);
  if (tid < 32) scratch[tid] = 1.0f / den;   // lanes 0..31: row = l31 = tid
  __syncthreads();
  float idr[16];
#pragma unroll
  for (int r = 0; r < 16; ++r) idr[r] = scratch[qrow[r]];

  float* Ob = Op + ((size_t)b * SS + q0) * DD + w * 64;
#pragma unroll
  for (int r = 0; r < 16; ++r) {
    Ob[(size_t)qrow[r] * DD + l31]      = O0[r] * idr[r];
    Ob[(size_t)qrow[r] * DD + 32 + l31] = O1[r] * idr[r];
  }
}

// ---------------- fallback (round-1 kernel, zero workspace) ----------------

#define QS_STRIDE 520
#define KS_STRIDE 72
#define VT_STRIDE 18
#define PS_STRIDE 136

typedef bf16 bf16x2 __attribute__((ext_vector_type(2)));

__device__ __forceinline__ f32x16 qk_tile(const float* __restrict__ Kb,
                                          const bf16* __restrict__ Qsl,
                                          bf16* __restrict__ KVw,
                                          int l31, int lh8, int lane) {
  f32x16 acc = {};
  for (int dc = 0; dc < DD; dc += 64) {
#pragma unroll
    for (int i = 0; i < 8; ++i) {
      int f = i * 64 + lane;
      int row = f >> 4;
      int c4 = (f & 15) * 4;
      float4 v = *(const float4*)(Kb + row * DD + dc + c4);
      bf16x4 h = { (bf16)v.x, (bf16)v.y, (bf16)v.z, (bf16)v.w };
      *(bf16x4*)&KVw[row * KS_STRIDE + c4] = h;
    }
#pragma unroll
    for (int ks = 0; ks < 4; ++ks) {
      bf16x8 a  = *(const bf16x8*)&Qsl[l31 * QS_STRIDE + dc + ks * 16 + lh8];
      bf16x8 bb = *(const bf16x8*)&KVw[l31 * KS_STRIDE + ks * 16 + lh8];
      acc = __builtin_amdgcn_mfma_f32_32x32x16_bf16(a, bb, acc, 0, 0, 0);
    }
  }
  return acc;
}

__launch_bounds__(256, 1)
__global__ void nm_attn_kernel(const float* __restrict__ Qp,
                               const float* __restrict__ Kp,
                               const float* __restrict__ Vp,
                               float* __restrict__ Op) {
  __shared__ bf16 Qs[32 * QS_STRIDE];
  __shared__ bf16 KVu[4][32 * KS_STRIDE];
  __shared__ bf16 Psl[32 * PS_STRIDE];
  __shared__ float redA[4][32];
  __shared__ float redB[4][32];
  __shared__ float a0v[32], a1v[32], idv[32];

  const int tid  = threadIdx.x;
  const int w    = tid >> 6;
  const int lane = tid & 63;
  const int l31  = lane & 31;
  const int lh   = lane >> 5;
  const int lh8  = lh * 8;
  const int b    = blockIdx.y;
  const int q0   = blockIdx.x * 32;

  {
    const float* Qbase = Qp + (size_t)(b * SS + q0) * DD;
#pragma unroll
    for (int i = 0; i < 16; ++i) {
      int f = i * 256 + tid;
      int row = f >> 7;
      int c4 = (f & 127) * 4;
      float4 v = *(const float4*)(Qbase + row * DD + c4);
      bf16x4 h = { (bf16)v.x, (bf16)v.y, (bf16)v.z, (bf16)v.w };
      *(bf16x4*)&Qs[row * QS_STRIDE + c4] = h;
    }
  }
  __syncthreads();

  int qrow[16];
#pragma unroll
  for (int r = 0; r < 16; ++r) qrow[r] = (r & 3) + 8 * (r >> 2) + 4 * lh;

  float sumv[16], sqv[16];
#pragma unroll
  for (int r = 0; r < 16; ++r) { sumv[r] = 0.f; sqv[r] = 0.f; }

  for (int kt = 0; kt < 16; ++kt) {
    const float* Kb = Kp + (size_t)(b * SS + kt * 128 + w * 32) * DD;
    f32x16 acc = qk_tile(Kb, Qs, KVu[w], l31, lh8, lane);
#pragma unroll
    for (int r = 0; r < 16; ++r) {
      float s = acc[r] * SCALE;
      sumv[r] += s;
      sqv[r]  += s * s;
    }
  }

#pragma unroll
  for (int r = 0; r < 16; ++r) {
    float v1 = sumv[r], v2 = sqv[r];
#pragma unroll
    for (int m = 16; m >= 1; m >>= 1) {
      v1 += __shfl_xor(v1, m);
      v2 += __shfl_xor(v2, m);
    }
    if (l31 == 0) { redA[w][qrow[r]] = v1; redB[w][qrow[r]] = v2; }
  }
  __syncthreads();
  if (tid < 32) {
    float s  = redA[0][tid] + redA[1][tid] + redA[2][tid] + redA[3][tid];
    float sq = redB[0][tid] + redB[1][tid] + redB[2][tid] + redB[3][tid];
    float mean = s * (1.0f / 2048.0f);
    float var = (sq - 2048.0f * mean * mean) * (1.0f / 2047.0f);
    var = fmaxf(var, 0.0f);
    float istd = 1.0f / (sqrtf(var) + 1e-6f);
    a1v[tid] = istd * LOG2E;
    a0v[tid] = -mean * istd * LOG2E;
  }
  __syncthreads();

  float a0r[16], a1r[16], den[16];
#pragma unroll
  for (int r = 0; r < 16; ++r) {
    a0r[r] = a0v[qrow[r]];
    a1r[r] = a1v[qrow[r]];
    den[r] = 0.f;
  }

  f32x16 Oa[4] = {};

  for (int kt = 0; kt < 16; ++kt) {
    const float* Kb = Kp + (size_t)(b * SS + kt * 128 + w * 32) * DD;
    f32x16 acc = qk_tile(Kb, Qs, KVu[w], l31, lh8, lane);

    __syncthreads();
#pragma unroll
    for (int r = 0; r < 16; ++r) {
      float s = acc[r] * SCALE;
      float p = exp2f(fmaf(s, a1r[r], a0r[r]));
      den[r] += p;
      Psl[qrow[r] * PS_STRIDE + w * 32 + l31] = (bf16)p;
    }
    __syncthreads();

    const float* Vb = Vp + (size_t)(b * SS + kt * 128) * DD + w * 128 + 2 * lane;
    bf16* Vt = KVu[w];
    const int d0 = 2 * lane;
    for (int ks2 = 0; ks2 < 8; ++ks2) {
      const float* Vk = Vb + ks2 * 16 * DD;
#pragma unroll
      for (int i = 0; i < 8; ++i) {
        float2 va = *(const float2*)(Vk + (2 * i) * DD);
        float2 vc = *(const float2*)(Vk + (2 * i + 1) * DD);
        bf16x2 h0 = { (bf16)va.x, (bf16)vc.x };
        bf16x2 h1 = { (bf16)va.y, (bf16)vc.y };
        *(bf16x2*)&Vt[d0 * VT_STRIDE + 2 * i] = h0;
        *(bf16x2*)&Vt[(d0 + 1) * VT_STRIDE + 2 * i] = h1;
      }
      bf16x8 aP = *(const bf16x8*)&Psl[l31 * PS_STRIDE + ks2 * 16 + lh8];
#pragma unroll
      for (int dt = 0; dt < 4; ++dt) {
        const bf16* vr = &Vt[(dt * 32 + l31) * VT_STRIDE + lh8];
        bf16x2 e0 = *(const bf16x2*)(vr + 0);
        bf16x2 e1 = *(const bf16x2*)(vr + 2);
        bf16x2 e2 = *(const bf16x2*)(vr + 4);
        bf16x2 e3 = *(const bf16x2*)(vr + 6);
        bf16x8 bV = { e0.x, e0.y, e1.x, e1.y, e2.x, e2.y, e3.x, e3.y };
        Oa[dt] = __builtin_amdgcn_mfma_f32_32x32x16_bf16(aP, bV, Oa[dt], 0, 0, 0);
      }
    }
  }

#pragma unroll
  for (int r = 0; r < 16; ++r) {
    float v1 = den[r];
#pragma unroll
    for (int m = 16; m >= 1; m >>= 1) v1 += __shfl_xor(v1, m);
    if (l31 == 0) redA[w][qrow[r]] = v1;
  }
  __syncthreads();
  if (tid < 32) {
    float t = redA[0][tid] + redA[1][tid] + redA[2][tid] + redA[3][tid];
    idv[tid] = 1.0f / t;
  }
  __syncthreads();

  float idr[16];
#pragma unroll
  for (int r = 0; r < 16; ++r) idr[r] = idv[qrow[r]];

  float* Ob = Op + (size_t)(b * SS + q0) * DD + w * 128;
#pragma unroll
  for (int dt = 0; dt < 4; ++dt) {
#pragma unroll
    for (int r = 0; r < 16; ++r) {
      Ob[qrow[r] * DD + dt * 32 + l31] = Oa[dt][r] * idr[r];
    }
  }
}

// ---------------- launcher ----------------

extern "C" void kernel_launch(void* const* d_in, const int* in_sizes, int n_in,
                              void* d_out, int out_size, void* d_ws, size_t ws_size,
                              hipStream_t stream) {
  const float* Q = (const float*)d_in[0];
  const float* K = (const float*)d_in[1];
  const float* V = (const float*)d_in[2];
  float* out = (float*)d_out;
  (void)in_sizes; (void)n_in; (void)out_size;

  const size_t elems = (size_t)BB * SS * DD;           // 4,194,304
  const size_t need  = 3 * elems * sizeof(bf16);       // 25,165,824 B

  if (ws_size >= need) {
    bf16* Kb = (bf16*)d_ws;
    bf16* Qb = Kb + elems;
    bf16* Vt = Qb + elems;
    cast_qk_kernel<<<(int)(elems / 8 / 256), 256, 0, stream>>>(Q, K, Qb, Kb);
    transpose_v_kernel<<<dim3(SS / 32, DD / 32, BB), 256, 0, stream>>>(V, Vt);
    nm_attn2_kernel<<<256, 512, 0, stream>>>(Qb, Kb, Vt, out);
  } else {
    nm_attn_kernel<<<dim3(SS / 32, BB), dim3(256, 1, 1), 0, stream>>>(Q, K, V, out);
  }
}